// Round 2
// baseline (620.734 us; speedup 1.0000x reference)
//
#include <hip/hip_runtime.h>

#define B_    32
#define S_    64
#define D_    8
#define NE_   512        // S_*D_
#define E_    150000
#define NSEG  (B_*NE_)   // 16384
#define FLAG_OFF ((size_t)NSEG * 33)   // float-index of dtype flag in ws

__device__ __forceinline__ float bf2f(unsigned int u) {
    union { unsigned int u; float f; } cv; cv.u = u << 16; return cv.f;
}
__device__ __forceinline__ unsigned short f2bf(float f) {
    union { float f; unsigned int u; } cv; cv.f = f;
    unsigned int u = cv.u;
    return (unsigned short)((u + 0x7fffu + ((u >> 16) & 1u)) >> 16);
}
__device__ __forceinline__ void unpack8(const uint4 v, float* __restrict__ f) {
    f[0] = bf2f(v.x & 0xffffu); f[1] = bf2f(v.x >> 16);
    f[2] = bf2f(v.y & 0xffffu); f[3] = bf2f(v.y >> 16);
    f[4] = bf2f(v.z & 0xffffu); f[5] = bf2f(v.z >> 16);
    f[6] = bf2f(v.w & 0xffffu); f[7] = bf2f(v.w >> 16);
}

// Load 8 consecutive float values (element offset eoff, must be multiple of 8).
template<bool BF>
__device__ __forceinline__ void load8(const void* __restrict__ base, size_t eoff,
                                      float* __restrict__ f) {
    if (BF) {
        uint4 v = *(const uint4*)((const unsigned short*)base + eoff);
        unpack8(v, f);
    } else {
        const float4* p = (const float4*)((const float*)base + eoff);
        float4 a = p[0], b = p[1];
        f[0] = a.x; f[1] = a.y; f[2] = a.z; f[3] = a.w;
        f[4] = b.x; f[5] = b.y; f[6] = b.z; f[7] = b.w;
    }
}
template<bool BF>
__device__ __forceinline__ void load16(const void* base, size_t eoff, float* f) {
    load8<BF>(base, eoff, f); load8<BF>(base, eoff + 8, f + 8);
}
template<bool BF>
__device__ __forceinline__ void load32(const void* base, size_t eoff, float* f) {
    load8<BF>(base, eoff, f);       load8<BF>(base, eoff + 8, f + 8);
    load8<BF>(base, eoff + 16, f + 16); load8<BF>(base, eoff + 24, f + 24);
}
template<bool BF>
__device__ __forceinline__ void store16(void* out, size_t eoff, const float* v) {
    if (BF) {
        unsigned int res[8];
        #pragma unroll
        for (int o = 0; o < 16; o += 2) {
            unsigned int lo = (unsigned int)f2bf(v[o]);
            unsigned int hi = (unsigned int)f2bf(v[o + 1]);
            res[o >> 1] = lo | (hi << 16);
        }
        uint4* p = (uint4*)((unsigned short*)out + eoff);
        p[0] = make_uint4(res[0], res[1], res[2], res[3]);
        p[1] = make_uint4(res[4], res[5], res[6], res[7]);
    } else {
        float4* p = (float4*)((float*)out + eoff);
        #pragma unroll
        for (int k = 0; k < 4; ++k)
            p[k] = make_float4(v[4 * k], v[4 * k + 1], v[4 * k + 2], v[4 * k + 3]);
    }
}

// --- dtype detection: low short of each 32-bit word. bf16 data -> real bf16
// values (exp field ~[116,127]); fp32 data -> uniform mantissa bits (~17% hit).
__global__ void detect_dtype(const unsigned int* __restrict__ w, int* __restrict__ flag) {
    __shared__ int cnt_s;
    if (threadIdx.x == 0) cnt_s = 0;
    __syncthreads();
    int ok = 0;
    #pragma unroll
    for (int k = 0; k < 4; ++k) {
        unsigned int word = w[threadIdx.x * 4 + k];
        unsigned int s = word & 0xFFFFu;
        unsigned int e = (s >> 7) & 0xFFu;
        if (s == 0u || (e >= 90u && e <= 132u)) ok++;
    }
    atomicAdd(&cnt_s, ok);
    __syncthreads();
    if (threadIdx.x == 0) *flag = (cnt_s >= 200) ? 1 : 0;   // 1 = bf16
}

// ws layout: sums[NSEG*32] fp32, cnt[NSEG] fp32, flag int.
__global__ void zero_ws(float4* __restrict__ ws) {
    size_t i = (size_t)blockIdx.x * blockDim.x + threadIdx.x;
    ws[i] = make_float4(0.f, 0.f, 0.f, 0.f);
}

template<bool BF>
__device__ __forceinline__ void edge_body(const void* __restrict__ nf,
                                          const void* __restrict__ W0,
                                          const void* __restrict__ b0,
                                          const void* __restrict__ W1,
                                          const void* __restrict__ b1,
                                          const int* __restrict__ inc,
                                          float* __restrict__ sums,
                                          float* __restrict__ cnt, int e) {
    const int4 c = ((const int4*)inc)[e];     // c0,c1,c2,c3
    const int eidx = c.z * D_ + c.w;

    float x[16];
    load16<BF>(nf, (size_t)(c.y * S_ + c.z) * 16, x);

    float h[32];
    {
        float bb[32];
        load32<BF>(b0, (size_t)eidx * 32, bb);
        #pragma unroll 4
        for (int o = 0; o < 32; ++o) {
            float wf[16];
            load16<BF>(W0, (size_t)eidx * 512 + o * 16, wf);
            float acc = bb[o];
            #pragma unroll
            for (int i = 0; i < 16; ++i) acc = fmaf(wf[i], x[i], acc);
            h[o] = fmaxf(acc, 0.f);
        }
    }
    float h2[32];
    {
        float bb[32];
        load32<BF>(b1, (size_t)eidx * 32, bb);
        #pragma unroll 4
        for (int o = 0; o < 32; ++o) {
            float wf[32];
            load32<BF>(W1, (size_t)eidx * 1024 + o * 32, wf);
            float acc = bb[o];
            #pragma unroll
            for (int i = 0; i < 32; ++i) acc = fmaf(wf[i], h[i], acc);
            h2[o] = fmaxf(acc, 0.f);
        }
    }
    const int seg = c.x * NE_ + eidx;
    float* sp = sums + (size_t)seg * 32;
    #pragma unroll
    for (int o = 0; o < 32; ++o) atomicAdd(sp + o, h2[o]);
    atomicAdd(cnt + seg, 1.0f);
}

__global__ void edge_kernel(const void* nf, const void* W0, const void* b0,
                            const void* W1, const void* b1,
                            const int* __restrict__ inc,
                            float* sums, float* cnt, const int* __restrict__ flag) {
    int e = blockIdx.x * blockDim.x + threadIdx.x;
    if (e >= E_) return;
    if (*flag) edge_body<true >(nf, W0, b0, W1, b1, inc, sums, cnt, e);
    else       edge_body<false>(nf, W0, b0, W1, b1, inc, sums, cnt, e);
}

template<bool BF>
__device__ __forceinline__ void out_body(const float* __restrict__ sums,
                                         const float* __restrict__ cnt,
                                         const void* __restrict__ W0,
                                         const void* __restrict__ b0,
                                         const void* __restrict__ W1,
                                         const void* __restrict__ b1,
                                         void* __restrict__ out, int seg) {
    const int e = seg & (NE_ - 1);
    float cv = cnt[seg];
    float inv = cv > 0.f ? 1.0f / cv : 0.0f;

    float ef[32];
    {
        const float4* sp = (const float4*)(sums + (size_t)seg * 32);
        #pragma unroll
        for (int i = 0; i < 8; ++i) {
            float4 v = sp[i];
            ef[4 * i + 0] = v.x * inv; ef[4 * i + 1] = v.y * inv;
            ef[4 * i + 2] = v.z * inv; ef[4 * i + 3] = v.w * inv;
        }
    }
    float h[32];
    {
        float bb[32];
        load32<BF>(b0, (size_t)e * 32, bb);
        #pragma unroll 4
        for (int o = 0; o < 32; ++o) {
            float wf[32];
            load32<BF>(W0, (size_t)e * 1024 + o * 32, wf);
            float acc = bb[o];
            #pragma unroll
            for (int i = 0; i < 32; ++i) acc = fmaf(wf[i], ef[i], acc);
            h[o] = fmaxf(acc, 0.f);
        }
    }
    float r[16];
    {
        float bb[16];
        load16<BF>(b1, (size_t)e * 16, bb);
        #pragma unroll 4
        for (int o = 0; o < 16; ++o) {
            float wf[32];
            load32<BF>(W1, (size_t)e * 512 + o * 32, wf);
            float acc = bb[o];
            #pragma unroll
            for (int i = 0; i < 32; ++i) acc = fmaf(wf[i], h[i], acc);
            r[o] = fmaxf(acc, 0.f);
        }
    }
    store16<BF>(out, (size_t)seg * 16, r);
}

__global__ void out_kernel(const float* __restrict__ sums, const float* __restrict__ cnt,
                           const void* W0, const void* b0, const void* W1, const void* b1,
                           void* out, const int* __restrict__ flag) {
    int seg = blockIdx.x * blockDim.x + threadIdx.x;
    if (seg >= NSEG) return;
    if (*flag) out_body<true >(sums, cnt, W0, b0, W1, b1, out, seg);
    else       out_body<false>(sums, cnt, W0, b0, W1, b1, out, seg);
}

extern "C" void kernel_launch(void* const* d_in, const int* in_sizes, int n_in,
                              void* d_out, int out_size, void* d_ws, size_t ws_size,
                              hipStream_t stream) {
    const void* nf  = d_in[0];
    const void* iw0 = d_in[1];
    const void* ib0 = d_in[2];
    const void* iw1 = d_in[3];
    const void* ib1 = d_in[4];
    const void* ow0 = d_in[5];
    const void* ob0 = d_in[6];
    const void* ow1 = d_in[7];
    const void* ob1 = d_in[8];
    const int* inc = (const int*)d_in[9];

    float* sums = (float*)d_ws;
    float* cnt  = sums + (size_t)NSEG * 32;
    int*   flag = (int*)((float*)d_ws + FLAG_OFF);

    detect_dtype<<<1, 64, 0, stream>>>((const unsigned int*)iw0, flag);
    zero_ws<<<528, 256, 0, stream>>>((float4*)d_ws);
    edge_kernel<<<(E_ + 255) / 256, 256, 0, stream>>>(nf, iw0, ib0, iw1, ib1, inc,
                                                      sums, cnt, flag);
    out_kernel<<<NSEG / 256, 256, 0, stream>>>(sums, cnt, ow0, ob0, ow1, ob1,
                                               d_out, flag);
}

// Round 3
// 176.601 us; speedup vs baseline: 3.5149x; 3.5149x over previous
//
#include <hip/hip_runtime.h>

#define B_    32
#define S_    64
#define D_    8
#define NE_   512        // S_*D_
#define E_    150000
#define CAP   512        // payload slots per eidx bin (mean 293, 9+ sigma headroom)

// ws layout: cursor[NE_] int, then payload[NE_*CAP] int.

__global__ void zero_cursor(int* __restrict__ cursor) {
    cursor[threadIdx.x + blockIdx.x * blockDim.x] = 0;
}

__global__ void scatter_kernel(const int* __restrict__ inc,
                               int* __restrict__ cursor,
                               int* __restrict__ payload) {
    int e = blockIdx.x * blockDim.x + threadIdx.x;
    if (e >= E_) return;
    const int4 c = ((const int4*)inc)[e];      // c0=batch, c1=node, c2, c3
    const int eidx = c.z * D_ + c.w;
    const int pos = atomicAdd(&cursor[eidx], 1);
    if (pos < CAP)
        payload[eidx * CAP + pos] = (c.x << 16) | (c.y * S_ + c.z);
}

__global__ __launch_bounds__(256)
void main_kernel(const float* __restrict__ nf,
                 const float* __restrict__ iw0, const float* __restrict__ ib0,
                 const float* __restrict__ iw1, const float* __restrict__ ib1,
                 const float* __restrict__ ow0, const float* __restrict__ ob0,
                 const float* __restrict__ ow1, const float* __restrict__ ob1,
                 const int* __restrict__ cursor, const int* __restrict__ payload,
                 float* __restrict__ out) {
    const int eidx = blockIdx.x;
    const int tid  = threadIdx.x;

    __shared__ __align__(16) float w0[512];    // in_core0[eidx]  (32x16)
    __shared__ __align__(16) float bs0[32];
    __shared__ __align__(16) float w1[1024];   // in_core1[eidx]  (32x32)
    __shared__ __align__(16) float bs1[32];
    __shared__ __align__(16) float q0[1024];   // out_core0[eidx] (32x32)
    __shared__ __align__(16) float qb0[32];
    __shared__ __align__(16) float q1[512];    // out_core1[eidx] (16x32)
    __shared__ __align__(16) float qb1[16];
    __shared__ float acc[32][33];              // per-batch sums (+1 pad)
    __shared__ float hb[32][33];               // out-MLP hidden
    __shared__ float cnts[32];

    // --- stage weights to LDS (coalesced dword loads) ---
    {
        const float* s0 = iw0 + (size_t)eidx * 512;
        const float* s1 = iw1 + (size_t)eidx * 1024;
        const float* s2 = ow0 + (size_t)eidx * 1024;
        const float* s3 = ow1 + (size_t)eidx * 512;
        for (int i = tid; i < 512;  i += 256) w0[i] = s0[i];
        for (int i = tid; i < 1024; i += 256) w1[i] = s1[i];
        for (int i = tid; i < 1024; i += 256) q0[i] = s2[i];
        for (int i = tid; i < 512;  i += 256) q1[i] = s3[i];
        if (tid < 32) {
            bs0[tid] = ib0[(size_t)eidx * 32 + tid];
            bs1[tid] = ib1[(size_t)eidx * 32 + tid];
            qb0[tid] = ob0[(size_t)eidx * 32 + tid];
            cnts[tid] = 0.f;
        } else if (tid < 48) {
            qb1[tid - 32] = ob1[(size_t)eidx * 16 + (tid - 32)];
        }
        for (int i = tid; i < 32 * 33; i += 256) ((float*)acc)[i] = 0.f;
    }
    __syncthreads();

    // --- per-edge MLP + LDS accumulation ---
    const int n = min(cursor[eidx], CAP);
    for (int i = tid; i < n; i += 256) {
        const int p   = payload[eidx * CAP + i];
        const int b   = p >> 16;
        const int row = p & 0xFFFF;

        float x[16];
        {
            const float4* xp = (const float4*)(nf + (size_t)row * 16);
            #pragma unroll
            for (int k = 0; k < 4; ++k) {
                float4 v = xp[k];
                x[4*k] = v.x; x[4*k+1] = v.y; x[4*k+2] = v.z; x[4*k+3] = v.w;
            }
        }
        float h[32];
        #pragma unroll 4
        for (int o = 0; o < 32; ++o) {
            float a = bs0[o];
            #pragma unroll
            for (int k = 0; k < 16; ++k) a = fmaf(w0[o * 16 + k], x[k], a);
            h[o] = fmaxf(a, 0.f);
        }
        float h2[32];
        #pragma unroll 4
        for (int o = 0; o < 32; ++o) {
            float a = bs1[o];
            #pragma unroll
            for (int k = 0; k < 32; ++k) a = fmaf(w1[o * 32 + k], h[k], a);
            h2[o] = fmaxf(a, 0.f);
        }
        #pragma unroll
        for (int o = 0; o < 32; ++o) atomicAdd(&acc[b][o], h2[o]);
        atomicAdd(&cnts[b], 1.f);
    }
    __syncthreads();

    // --- mean + out layer 0: thread t -> batch b = t>>3, outputs 4*(t&7).. ---
    {
        const int b  = tid >> 3;
        const int o0 = (tid & 7) * 4;
        const float cv  = cnts[b];
        const float inv = cv > 0.f ? 1.0f / cv : 0.0f;
        #pragma unroll
        for (int j = 0; j < 4; ++j) {
            const int o = o0 + j;
            float d = 0.f;
            #pragma unroll
            for (int k = 0; k < 32; ++k) d = fmaf(q0[o * 32 + k], acc[b][k], d);
            hb[b][o] = fmaxf(fmaf(d, inv, qb0[o]), 0.f);
        }
    }
    __syncthreads();

    // --- out layer 1: thread t -> batch b = t>>3, outputs 2*(t&7).. ---
    {
        const int b  = tid >> 3;
        const int o0 = (tid & 7) * 2;
        float r[2];
        #pragma unroll
        for (int j = 0; j < 2; ++j) {
            const int o = o0 + j;
            float d = qb1[o];
            #pragma unroll
            for (int k = 0; k < 32; ++k) d = fmaf(q1[o * 32 + k], hb[b][k], d);
            r[j] = fmaxf(d, 0.f);
        }
        float2* op = (float2*)(out + ((size_t)b * NE_ + eidx) * 16 + o0);
        *op = make_float2(r[0], r[1]);
    }
}

extern "C" void kernel_launch(void* const* d_in, const int* in_sizes, int n_in,
                              void* d_out, int out_size, void* d_ws, size_t ws_size,
                              hipStream_t stream) {
    const float* nf  = (const float*)d_in[0];
    const float* iw0 = (const float*)d_in[1];
    const float* ib0 = (const float*)d_in[2];
    const float* iw1 = (const float*)d_in[3];
    const float* ib1 = (const float*)d_in[4];
    const float* ow0 = (const float*)d_in[5];
    const float* ob0 = (const float*)d_in[6];
    const float* ow1 = (const float*)d_in[7];
    const float* ob1 = (const float*)d_in[8];
    const int*   inc = (const int*)d_in[9];

    int* cursor  = (int*)d_ws;
    int* payload = cursor + NE_;

    zero_cursor<<<2, 256, 0, stream>>>(cursor);
    scatter_kernel<<<(E_ + 255) / 256, 256, 0, stream>>>(inc, cursor, payload);
    main_kernel<<<NE_, 256, 0, stream>>>(nf, iw0, ib0, iw1, ib1,
                                         ow0, ob0, ow1, ob1,
                                         cursor, payload, (float*)d_out);
}

// Round 4
// 145.695 us; speedup vs baseline: 4.2605x; 1.2121x over previous
//
#include <hip/hip_runtime.h>

#define B_    32
#define S_    64
#define D_    8
#define NE_   512        // S_*D_
#define E_    150000
#define CAP   512        // payload slots per eidx bin (mean 293)

#define SCAT_BLK  1024
#define SCAT_R    4
#define SCAT_EPB  (SCAT_BLK*SCAT_R)                  // 4096 edges/block
#define SCAT_NB   ((E_ + SCAT_EPB - 1)/SCAT_EPB)     // 37 blocks

// ws layout: cursor[NE_] int, then payload[NE_*CAP] int.

__global__ void zero_cursor(int* __restrict__ cursor) {
    cursor[threadIdx.x] = 0;
}

__global__ __launch_bounds__(SCAT_BLK)
void scatter_kernel(const int* __restrict__ inc,
                    int* __restrict__ cursor,
                    int* __restrict__ payload) {
    __shared__ int lcount[NE_];
    __shared__ int lbase[NE_];
    __shared__ int stash_p[SCAT_EPB];
    __shared__ int stash_m[SCAT_EPB];    // (eidx<<16)|lpos, or -1
    const int tid = threadIdx.x;

    for (int i = tid; i < NE_; i += SCAT_BLK) lcount[i] = 0;
    __syncthreads();

    #pragma unroll
    for (int r = 0; r < SCAT_R; ++r) {
        const int e = blockIdx.x * SCAT_EPB + r * SCAT_BLK + tid;
        int m = -1, p = 0;
        if (e < E_) {
            const int4 c = ((const int4*)inc)[e];   // c0=batch c1=node c2 c3
            const int eidx = c.z * D_ + c.w;
            const int lpos = atomicAdd(&lcount[eidx], 1);   // LDS atomic, light
            m = (eidx << 16) | lpos;
            p = (c.x << 16) | (c.y * S_ + c.z);
        }
        stash_m[r * SCAT_BLK + tid] = m;
        stash_p[r * SCAT_BLK + tid] = p;
    }
    __syncthreads();

    // one global atomic per occupied bin per block (~19K total, 37-way contention)
    for (int i = tid; i < NE_; i += SCAT_BLK) {
        const int c = lcount[i];
        lbase[i] = (c > 0) ? atomicAdd(&cursor[i], c) : 0;
    }
    __syncthreads();

    #pragma unroll
    for (int r = 0; r < SCAT_R; ++r) {
        const int m = stash_m[r * SCAT_BLK + tid];
        if (m >= 0) {
            const int eidx = m >> 16;
            const int idx  = lbase[eidx] + (m & 0xFFFF);
            if (idx < CAP) payload[eidx * CAP + idx] = stash_p[r * SCAT_BLK + tid];
        }
    }
}

__global__ __launch_bounds__(256)
void main_kernel(const float* __restrict__ nf,
                 const float* __restrict__ iw0, const float* __restrict__ ib0,
                 const float* __restrict__ iw1, const float* __restrict__ ib1,
                 const float* __restrict__ ow0, const float* __restrict__ ob0,
                 const float* __restrict__ ow1, const float* __restrict__ ob1,
                 const int* __restrict__ cursor, const int* __restrict__ payload,
                 float* __restrict__ out) {
    const int eidx = blockIdx.x;
    const int tid  = threadIdx.x;

    __shared__ float acc[32][33];              // per-batch sums (+1 pad)
    __shared__ float hb[32][33];               // out-MLP hidden
    __shared__ float cnts[32];
    __shared__ __align__(16) float q0s[1024];  // out_core0[eidx] (32x32)
    __shared__ __align__(16) float q1s[512];   // out_core1[eidx] (16x32)
    __shared__ float qb0s[32], qb1s[16];

    // in-MLP weights: indices are wave-uniform (eidx from blockIdx) -> s_load path
    const float* __restrict__ w0  = iw0 + (size_t)eidx * 512;   // 32x16
    const float* __restrict__ bb0 = ib0 + (size_t)eidx * 32;
    const float* __restrict__ w1  = iw1 + (size_t)eidx * 1024;  // 32x32
    const float* __restrict__ bb1 = ib1 + (size_t)eidx * 32;

    // stage out-MLP weights (lane-dependent use later) into LDS, once
    for (int i = tid; i < 1024; i += 256) q0s[i] = ow0[(size_t)eidx * 1024 + i];
    for (int i = tid; i < 512;  i += 256) q1s[i] = ow1[(size_t)eidx * 512 + i];
    if (tid < 32) { qb0s[tid] = ob0[(size_t)eidx * 32 + tid]; cnts[tid] = 0.f; }
    else if (tid < 48) qb1s[tid - 32] = ob1[(size_t)eidx * 16 + (tid - 32)];
    for (int i = tid; i < 32 * 33; i += 256) ((float*)acc)[i] = 0.f;
    __syncthreads();

    const int n = min(cursor[eidx], CAP);
    for (int i = tid; i < n; i += 256) {
        const int p   = payload[eidx * CAP + i];
        const int b   = p >> 16;
        const int row = p & 0xFFFF;

        float x[16];
        {
            const float4* xp = (const float4*)(nf + (size_t)row * 16);
            #pragma unroll
            for (int k = 0; k < 4; ++k) {
                float4 v = xp[k];
                x[4*k] = v.x; x[4*k+1] = v.y; x[4*k+2] = v.z; x[4*k+3] = v.w;
            }
        }
        float h[32];
        #pragma unroll 4
        for (int o = 0; o < 32; ++o) {
            float a = bb0[o];
            #pragma unroll
            for (int k = 0; k < 16; ++k) a = fmaf(w0[o * 16 + k], x[k], a);
            h[o] = fmaxf(a, 0.f);
        }
        float h2[32];
        #pragma unroll 4
        for (int o = 0; o < 32; ++o) {
            float a = bb1[o];
            #pragma unroll
            for (int k = 0; k < 32; ++k) a = fmaf(w1[o * 32 + k], h[k], a);
            h2[o] = fmaxf(a, 0.f);
        }
        #pragma unroll
        for (int o = 0; o < 32; ++o) atomicAdd(&acc[b][o], h2[o]);
        atomicAdd(&cnts[b], 1.f);
    }
    __syncthreads();

    // mean + out layer 0: thread t -> batch b = t>>3, outputs 4*(t&7)..
    {
        const int b  = tid >> 3;
        const int o0 = (tid & 7) * 4;
        const float cv  = cnts[b];
        const float inv = cv > 0.f ? 1.0f / cv : 0.0f;
        #pragma unroll
        for (int j = 0; j < 4; ++j) {
            const int o = o0 + j;
            float d = 0.f;
            #pragma unroll
            for (int k = 0; k < 32; ++k) d = fmaf(q0s[o * 32 + k], acc[b][k], d);
            hb[b][o] = fmaxf(fmaf(d, inv, qb0s[o]), 0.f);
        }
    }
    __syncthreads();

    // out layer 1: thread t -> batch b = t>>3, outputs 2*(t&7)..
    {
        const int b  = tid >> 3;
        const int o0 = (tid & 7) * 2;
        float r[2];
        #pragma unroll
        for (int j = 0; j < 2; ++j) {
            const int o = o0 + j;
            float d = qb1s[o];
            #pragma unroll
            for (int k = 0; k < 32; ++k) d = fmaf(q1s[o * 32 + k], hb[b][k], d);
            r[j] = fmaxf(d, 0.f);
        }
        float2* op = (float2*)(out + ((size_t)b * NE_ + eidx) * 16 + o0);
        *op = make_float2(r[0], r[1]);
    }
}

extern "C" void kernel_launch(void* const* d_in, const int* in_sizes, int n_in,
                              void* d_out, int out_size, void* d_ws, size_t ws_size,
                              hipStream_t stream) {
    const float* nf  = (const float*)d_in[0];
    const float* iw0 = (const float*)d_in[1];
    const float* ib0 = (const float*)d_in[2];
    const float* iw1 = (const float*)d_in[3];
    const float* ib1 = (const float*)d_in[4];
    const float* ow0 = (const float*)d_in[5];
    const float* ob0 = (const float*)d_in[6];
    const float* ow1 = (const float*)d_in[7];
    const float* ob1 = (const float*)d_in[8];
    const int*   inc = (const int*)d_in[9];

    int* cursor  = (int*)d_ws;
    int* payload = cursor + NE_;

    zero_cursor<<<1, NE_, 0, stream>>>(cursor);
    scatter_kernel<<<SCAT_NB, SCAT_BLK, 0, stream>>>(inc, cursor, payload);
    main_kernel<<<NE_, 256, 0, stream>>>(nf, iw0, ib0, iw1, ib1,
                                         ow0, ob0, ow1, ob1,
                                         cursor, payload, (float*)d_out);
}